// Round 1
// baseline (153.470 us; speedup 1.0000x reference)
//
#include <hip/hip_runtime.h>

// out[n,o] = -sum_i |x[n,i]*mbin[i] - w[i,o]|, then *mbout[o], then LayerNorm over o.
// N=4096 tokens, Cin=Cout=512. VALU-bound (no fp32 MFMA on CDNA4; op isn't a MAC anyway).

constexpr int BM = 64, BN = 64, BK = 32;
constexpr int TM = 4, TN = 4;

__global__ __launch_bounds__(256, 2)
void adder_gemm(const float* __restrict__ x, const float* __restrict__ w,
                const float* __restrict__ mbin, const float* __restrict__ mbout,
                float* __restrict__ out, int N, int Cin, int Cout) {
  // xs transposed: xs[k][m]; +1 pad makes the staging ds_writes <=2-way conflicts (free)
  __shared__ float xs[BK][BM + 1];
  __shared__ float ws[BK][BN];

  const int tid = threadIdx.x;
  const int tx = tid & 15;   // 16 col-groups of 4
  const int ty = tid >> 4;   // 16 row-groups of 4
  const int bm = blockIdx.x * BM;
  const int bn = blockIdx.y * BN;

  float acc[TM][TN];
  #pragma unroll
  for (int a = 0; a < TM; ++a)
    #pragma unroll
    for (int b = 0; b < TN; ++b) acc[a][b] = 0.f;

  for (int k0 = 0; k0 < Cin; k0 += BK) {
    // --- stage x tile (64 rows x 32 k) and w tile (32 k x 64 cols), 2 float4 each/thread
    #pragma unroll
    for (int it = 0; it < 2; ++it) {
      const int f = tid + it * 256;
      // x: row = f>>3 (0..63), col = (f&7)*4 — coalesced 128B-per-8-lanes
      const int row = f >> 3;
      const int col = (f & 7) << 2;
      const float4 xv = *reinterpret_cast<const float4*>(&x[(size_t)(bm + row) * Cin + k0 + col]);
      const float4 bv = *reinterpret_cast<const float4*>(&mbin[k0 + col]);
      xs[col + 0][row] = xv.x * bv.x;
      xs[col + 1][row] = xv.y * bv.y;
      xs[col + 2][row] = xv.z * bv.z;
      xs[col + 3][row] = xv.w * bv.w;
      // w: wrow = f>>4 (0..31), wcol = (f&15)*4 — coalesced, conflict-free b128 ds_write
      const int wrow = f >> 4;
      const int wcol = (f & 15) << 2;
      *reinterpret_cast<float4*>(&ws[wrow][wcol]) =
          *reinterpret_cast<const float4*>(&w[(size_t)(k0 + wrow) * Cout + bn + wcol]);
    }
    __syncthreads();

    #pragma unroll
    for (int kk = 0; kk < BK; ++kk) {
      float xr[TM];
      #pragma unroll
      for (int a = 0; a < TM; ++a) xr[a] = xs[kk][ty * TM + a];  // 4-addr broadcast, free
      const float4 wv = *reinterpret_cast<const float4*>(&ws[kk][tx * TN]);  // b128, conflict-free
      const float wr[TN] = {wv.x, wv.y, wv.z, wv.w};
      #pragma unroll
      for (int a = 0; a < TM; ++a)
        #pragma unroll
        for (int b = 0; b < TN; ++b)
          acc[a][b] += fabsf(xr[a] - wr[b]);  // v_sub_f32 + v_add_f32 |mod|
    }
    __syncthreads();
  }

  // epilogue: out = -acc * mbout  (pre-LN value, LN kernel normalizes in place)
  const float4 mb = *reinterpret_cast<const float4*>(&mbout[bn + tx * TN]);
  #pragma unroll
  for (int a = 0; a < TM; ++a) {
    float4 o;
    o.x = -acc[a][0] * mb.x;
    o.y = -acc[a][1] * mb.y;
    o.z = -acc[a][2] * mb.z;
    o.w = -acc[a][3] * mb.w;
    *reinterpret_cast<float4*>(&out[(size_t)(bm + ty * TM + a) * Cout + bn + tx * TN]) = o;
  }
}

// In-place LayerNorm over the last dim (C=512). One wave per row, 8 f32/lane.
__global__ __launch_bounds__(256)
void ln_rows(float* __restrict__ out, const float* __restrict__ gamma,
             const float* __restrict__ beta, int N, int C) {
  const int wave = threadIdx.x >> 6;
  const int lane = threadIdx.x & 63;
  const int row = blockIdx.x * 4 + wave;
  if (row >= N) return;
  float* p = out + (size_t)row * C;

  float v[8];
  {
    const float4 a = *reinterpret_cast<const float4*>(&p[lane * 8]);
    const float4 b = *reinterpret_cast<const float4*>(&p[lane * 8 + 4]);
    v[0] = a.x; v[1] = a.y; v[2] = a.z; v[3] = a.w;
    v[4] = b.x; v[5] = b.y; v[6] = b.z; v[7] = b.w;
  }

  float s = 0.f;
  #pragma unroll
  for (int i = 0; i < 8; ++i) s += v[i];
  #pragma unroll
  for (int off = 32; off > 0; off >>= 1) s += __shfl_xor(s, off, 64);
  const float mean = s * (1.0f / 512.0f);

  float d2 = 0.f;
  #pragma unroll
  for (int i = 0; i < 8; ++i) {
    const float d = v[i] - mean;
    d2 += d * d;
  }
  #pragma unroll
  for (int off = 32; off > 0; off >>= 1) d2 += __shfl_xor(d2, off, 64);
  const float rstd = rsqrtf(d2 * (1.0f / 512.0f) + 1e-5f);

  const float4 g0 = *reinterpret_cast<const float4*>(&gamma[lane * 8]);
  const float4 g1 = *reinterpret_cast<const float4*>(&gamma[lane * 8 + 4]);
  const float4 b0 = *reinterpret_cast<const float4*>(&beta[lane * 8]);
  const float4 b1 = *reinterpret_cast<const float4*>(&beta[lane * 8 + 4]);
  const float gg[8] = {g0.x, g0.y, g0.z, g0.w, g1.x, g1.y, g1.z, g1.w};
  const float bb[8] = {b0.x, b0.y, b0.z, b0.w, b1.x, b1.y, b1.z, b1.w};

  float4 o0, o1;
  o0.x = (v[0] - mean) * rstd * gg[0] + bb[0];
  o0.y = (v[1] - mean) * rstd * gg[1] + bb[1];
  o0.z = (v[2] - mean) * rstd * gg[2] + bb[2];
  o0.w = (v[3] - mean) * rstd * gg[3] + bb[3];
  o1.x = (v[4] - mean) * rstd * gg[4] + bb[4];
  o1.y = (v[5] - mean) * rstd * gg[5] + bb[5];
  o1.z = (v[6] - mean) * rstd * gg[6] + bb[6];
  o1.w = (v[7] - mean) * rstd * gg[7] + bb[7];
  *reinterpret_cast<float4*>(&p[lane * 8]) = o0;
  *reinterpret_cast<float4*>(&p[lane * 8 + 4]) = o1;
}

extern "C" void kernel_launch(void* const* d_in, const int* in_sizes, int n_in,
                              void* d_out, int out_size, void* d_ws, size_t ws_size,
                              hipStream_t stream) {
  const float* x     = (const float*)d_in[0];
  const float* w     = (const float*)d_in[1];
  const float* mbin  = (const float*)d_in[2];
  const float* mbout = (const float*)d_in[3];
  const float* gamma = (const float*)d_in[4];
  const float* beta  = (const float*)d_in[5];
  float* out = (float*)d_out;

  const int Cin  = in_sizes[2];           // 512
  const int Cout = in_sizes[3];           // 512
  const int N    = in_sizes[0] / Cin;     // 4096 tokens

  dim3 grid(N / BM, Cout / BN);           // 64 x 8 = 512 blocks
  adder_gemm<<<grid, 256, 0, stream>>>(x, w, mbin, mbout, out, N, Cin, Cout);
  ln_rows<<<dim3((N + 3) / 4), 256, 0, stream>>>(out, gamma, beta, N, Cout);
}